// Round 1
// baseline (309.974 us; speedup 1.0000x reference)
//
#include <hip/hip_runtime.h>

// RGCN layer: out[i] = relu( x[i]@root + bias + sum_r mean_{j in N_r(i)} x[j]@W[r] )
//
// Two-phase (linearity) + SOURCE COMPACTION:
//   H rows [0,N) = bf16(x@root + bias); then per rel r one row per USED src:
//   bf16(x[src]@W[r]).  out[i] = relu( H[i] + sum_e (1/c) * H[hidx_e] )
// pk2 packs hidx(20b) | c(8b). gather: wave-uniform dst scalarized.
//
// gemm_h v6: DIRECT REGISTER->GLOBAL H STORE (no LDS repack, no per-tile
// barrier). R14 counters showed v5 latency-bound (38% HBM, MfmaUtil 10%,
// all pipes idle): the per-tile chain [MFMA -> 32x ds_write_b16 (4-way
// conflicts) -> barrier -> ds_read -> store] serialized 4 waves in lockstep.
// v6 stores acc pairs (col c, c+16) packed per u32 straight from registers:
// one dwordx4 per row-slice per lane, H row layout permuted as
//   u32 at index (l16*4+p) = { lo: col 32p+l16, hi: col 32p+l16+16 }.
// gather_out absorbs the permutation (it reads one u32/lane anyway) and
// writes two dwords per lane. Waves fully independent; zero LDS tiles.

#define D 128

typedef __attribute__((ext_vector_type(8))) short bf16x8;
typedef __attribute__((ext_vector_type(4))) float f32x4;
typedef __attribute__((ext_vector_type(4))) unsigned u32x4;

__device__ inline unsigned short f32_to_bf16(float f) {
    unsigned u = __float_as_uint(f);
    return (unsigned short)((u + 0x7FFF + ((u >> 16) & 1)) >> 16);   // RNE
}
__device__ inline float bf_lo(unsigned u) { return __uint_as_float(u << 16); }
__device__ inline float bf_hi(unsigned u) { return __uint_as_float(u & 0xFFFF0000u); }

// ---------------------------------------------------------------------------
// prep: XB = bf16(x); WT[seg][n][k] = bf16(Wseg[k][n]); zero c, G, cnt2
// ---------------------------------------------------------------------------
__global__ __launch_bounds__(256) void prep_all(
    const float* __restrict__ x, const float* __restrict__ W,
    const float* __restrict__ root,
    unsigned* __restrict__ XB, unsigned short* __restrict__ WT,
    int* __restrict__ c, int* __restrict__ G, int* __restrict__ cnt2,
    int nquads, int wt_total, int n_nodes, int n_rel)
{
    int i = blockIdx.x * 256 + threadIdx.x;
    if (i < nquads) {
        float4 v = ((const float4*)x)[i];
        unsigned w0 = (unsigned)f32_to_bf16(v.x) | ((unsigned)f32_to_bf16(v.y) << 16);
        unsigned w1 = (unsigned)f32_to_bf16(v.z) | ((unsigned)f32_to_bf16(v.w) << 16);
        ((uint2*)XB)[i] = make_uint2(w0, w1);
    }
    if (i < wt_total) {
        int seg = i >> 14, rem = i & 16383;
        int n = rem >> 7, k = rem & 127;
        float v = (seg == 0) ? root[k * D + n]
                             : W[(size_t)(seg - 1) * D * D + k * D + n];
        WT[i] = f32_to_bf16(v);
    }
    if (i < n_nodes * n_rel) c[i] = 0;
    if (i < n_nodes * (n_rel + 1)) G[i] = 0;
    if (i < n_nodes) cnt2[i] = 0;
}

// ---------------------------------------------------------------------------
__global__ __launch_bounds__(256) void edge_hist(
    const int* __restrict__ edge_index, const int* __restrict__ edge_type,
    int* __restrict__ c, int* __restrict__ G, int n_edges, int n_nodes, int n_rel)
{
    int e = blockIdx.x * 256 + threadIdx.x;
    if (e >= n_edges) return;
    int src = edge_index[e];
    int dst = edge_index[n_edges + e];
    int r   = edge_type[e];
    atomicAdd(&c[dst * n_rel + r], 1);
    atomicAdd(&G[dst], 1);                       // degree (CSR)
    G[n_nodes + r * n_nodes + src] = 1;          // used flag (benign race)
}

// ---------------------------------------------------------------------------
// Two-level exclusive scan over G[nG]. Consumers: S(i) = tmp[i] + offs[i>>10].
// ---------------------------------------------------------------------------
__global__ __launch_bounds__(1024) void scanA(
    const int* __restrict__ G, int* __restrict__ tmp, int* __restrict__ parts, int n)
{
    __shared__ int buf[2][1024];
    const int tid = threadIdx.x;
    int i = blockIdx.x * 1024 + tid;
    int v = (i < n) ? G[i] : 0;
    buf[0][tid] = v;
    __syncthreads();
    int pi = 0;
    for (int off = 1; off < 1024; off <<= 1) {
        int t = buf[pi][tid] + ((tid >= off) ? buf[pi][tid - off] : 0);
        buf[1 - pi][tid] = t;
        pi = 1 - pi;
        __syncthreads();
    }
    if (i < n) tmp[i] = buf[pi][tid] - v;
    if (tid == 1023) parts[blockIdx.x] = buf[pi][1023];
}

__global__ __launch_bounds__(1024) void scanB(
    const int* __restrict__ parts, int* __restrict__ offs,
    int* __restrict__ tot, int np)
{
    __shared__ int buf[2][1024];
    const int t = threadIdx.x;
    int v = (t < np) ? parts[t] : 0;
    buf[0][t] = v;
    __syncthreads();
    int pi = 0;
    for (int off = 1; off < 1024; off <<= 1) {
        int s = buf[pi][t] + ((t >= off) ? buf[pi][t - off] : 0);
        buf[1 - pi][t] = s;
        pi = 1 - pi;
        __syncthreads();
    }
    if (t < np) offs[t] = buf[pi][t] - v;
    if (t == 0) tot[0] = buf[pi][1023];          // n_edges + n_compact
}

// ---------------------------------------------------------------------------
// edge_bin: CSR-place each edge; pack hidx|c; build csrc (redundant stores ok)
// ---------------------------------------------------------------------------
__global__ __launch_bounds__(256) void edge_bin(
    const int* __restrict__ edge_index, const int* __restrict__ edge_type,
    const int* __restrict__ tmp, const int* __restrict__ offs,
    const int* __restrict__ c, int* __restrict__ cnt2,
    unsigned* __restrict__ pk2, int* __restrict__ csrc,
    int n_edges, int n_nodes, int n_rel)
{
    int e = blockIdx.x * 256 + threadIdx.x;
    if (e >= n_edges) return;
    int src = edge_index[e];
    int dst = edge_index[n_edges + e];
    int r   = edge_type[e];
    int pos = tmp[dst] + offs[dst >> 10] + atomicAdd(&cnt2[dst], 1);
    int gi  = n_nodes + r * n_nodes + src;
    int cidx = tmp[gi] + offs[gi >> 10] - n_edges;    // compact rel-row index
    int hidx = n_nodes + cidx;                        // < 2^20
    unsigned cc = (unsigned)c[dst * n_rel + r];
    if (cc > 255u) cc = 255u;
    pk2[pos] = (unsigned)hidx | (cc << 20);
    csrc[cidx] = src;                                 // same-value race: benign
}

// ---------------------------------------------------------------------------
// Phase 1 v6: flat-balanced H GEMM, register->global epilogue.
// grid (1024, 1). Flat tile space over all segments; equal contiguous chunk
// per block. B-frags register-resident, reloaded only at segment boundaries
// (<=2 per block). Distance-1 A-frag prefetch. No LDS tiles, no per-tile
// barrier: each wave owns 16 rows of every tile and runs independently.
// H row layout (permuted, absorbed by gather_out):
//   u32 index (l16*4 + p) within row = { lo: col 32p+l16, hi: col 32p+l16+16 }
// ---------------------------------------------------------------------------
__global__ __launch_bounds__(256, 2) void gemm_h(
    const unsigned* __restrict__ XB, const unsigned short* __restrict__ WT,
    const float* __restrict__ bias, const int* __restrict__ csrc,
    const int* __restrict__ tmp, const int* __restrict__ offs,
    const int* __restrict__ tot, unsigned short* __restrict__ H,
    int n_nodes, int n_edges, int n_rel)
{
    __shared__ int s_end[9];     // cumulative flat-tile end per seg
    __shared__ int s_cnt[9];     // row count per seg
    __shared__ int s_S0[9];      // csrc base per seg
    __shared__ int s_base[9];    // H base row per seg

    const int tid  = threadIdx.x;
    const int wave = tid >> 6;
    const int lane = tid & 63;
    const int l16  = lane & 15;
    const int quad = lane >> 4;
    const int row_off = wave * 16 + l16;
    const int cq8  = quad * 8;

    if (tid == 0) {
        int acc = 0;
        for (int s = 0; s <= n_rel; ++s) {
            int cnt, S0 = 0, base;
            if (s == 0) { cnt = n_nodes; base = 0; }
            else {
                int r = s - 1;
                int gi0 = n_nodes + r * n_nodes;
                S0 = tmp[gi0] + offs[gi0 >> 10] - n_edges;
                int S1 = (r == n_rel - 1)
                         ? (tot[0] - n_edges)
                         : (tmp[gi0 + n_nodes] + offs[(gi0 + n_nodes) >> 10] - n_edges);
                cnt = S1 - S0;
                base = n_nodes + S0;
            }
            acc += (cnt + 63) >> 6;
            s_end[s] = acc; s_cnt[s] = cnt; s_S0[s] = S0; s_base[s] = base;
        }
    }
    __syncthreads();

    const int nflat = s_end[n_rel];
    const int chunk = (nflat + gridDim.x - 1) / gridDim.x;
    const int ft0 = blockIdx.x * chunk;
    int ft1 = ft0 + chunk; if (ft1 > nflat) ft1 = nflat;
    if (ft0 >= ft1) return;

    auto resolve = [&](int ft, int& seg, int& lt) {
        int s = 0;
        while (ft >= s_end[s]) ++s;
        seg = s;
        lt = ft - (s ? s_end[s - 1] : 0);
    };
    auto load_node = [&](int seg, int lt) -> int {
        int lr = lt * 64 + row_off;
        if (lr >= s_cnt[seg]) return 0;
        return (seg == 0) ? lr : csrc[s_S0[seg] + lr];
    };
    auto load_af = [&](int seg, int lt, int node, bf16x8* fr) {
        int lr = lt * 64 + row_off;
        bool v = (lr < s_cnt[seg]);
        const unsigned short* xr = (const unsigned short*)XB + (size_t)node * D + cq8;
#pragma unroll
        for (int kc = 0; kc < 4; ++kc)
            fr[kc] = v ? *(const bf16x8*)(xr + kc * 32)
                       : (bf16x8){0, 0, 0, 0, 0, 0, 0, 0};
    };

    bf16x8 bfr[8][4];
    float bv[8];
    int cur_seg = -1;

    int segA, ltA;
    resolve(ft0, segA, ltA);
    int nodeA = load_node(segA, ltA);
    bf16x8 af[4];
    load_af(segA, ltA, nodeA, af);

    for (int ft = ft0; ft < ft1; ++ft) {
        const int seg = segA, lt = ltA;

        // prefetch next flat tile's A-frags (independent of B/seg state)
        const bool haveN = (ft + 1 < ft1);
        bf16x8 afn[4];
        int segN = 0, ltN = 0;
        if (haveN) {
            resolve(ft + 1, segN, ltN);
            int nodeN = load_node(segN, ltN);
            load_af(segN, ltN, nodeN, afn);
        }

        // (re)load B-frags + bias at segment boundary (<=2 per block)
        if (seg != cur_seg) {
            const unsigned short* Wseg = WT + (size_t)seg * D * D;
#pragma unroll
            for (int nt = 0; nt < 8; ++nt) {
                const unsigned short* bp = Wseg + (size_t)(nt * 16 + l16) * D + cq8;
#pragma unroll
                for (int kc = 0; kc < 4; ++kc)
                    bfr[nt][kc] = *(const bf16x8*)(bp + kc * 32);
                bv[nt] = (seg == 0) ? bias[nt * 16 + l16] : 0.f;
            }
            cur_seg = seg;
        }

        f32x4 acc[8];
#pragma unroll
        for (int nt = 0; nt < 8; ++nt) {
            acc[nt] = (f32x4){0.f, 0.f, 0.f, 0.f};
#pragma unroll
            for (int kc = 0; kc < 4; ++kc)
                acc[nt] = __builtin_amdgcn_mfma_f32_16x16x32_bf16(
                    af[kc], bfr[nt][kc], acc[nt], 0, 0, 0);
        }

        // Epilogue: pack (col 32p+l16, col 32p+l16+16) pairs -> u32, one
        // dwordx4 per owned row. Coalesces as 4x256B segments per inst.
        {
            const int rbase = lt * 64 + wave * 16 + quad * 4;
            unsigned short* Hrow =
                H + (size_t)(s_base[seg] + rbase) * D + (size_t)l16 * 8;
#pragma unroll
            for (int reg = 0; reg < 4; ++reg) {
                if (rbase + reg < s_cnt[seg]) {
                    u32x4 w;
#pragma unroll
                    for (int p = 0; p < 4; ++p) {
                        unsigned lo = f32_to_bf16(acc[2 * p][reg]     + bv[2 * p]);
                        unsigned hi = f32_to_bf16(acc[2 * p + 1][reg] + bv[2 * p + 1]);
                        w[p] = lo | (hi << 16);
                    }
                    *(u32x4*)(Hrow + (size_t)reg * D) = w;
                }
            }
        }

        if (haveN) {
            segA = segN; ltA = ltN;
#pragma unroll
            for (int kc = 0; kc < 4; ++kc) af[kc] = afn[kc];
        }
    }
}

// ---------------------------------------------------------------------------
// Phase 2: one wave per dst node; dst made explicitly wave-uniform so
// pk2/bounds go through scalar loads; per-lane work = H load + 2 unpack +
// 2 FMA per edge. 1/c via v_rcp (c is a small integer: error ~1 ulp).
// H columns are permuted (see gemm_h): lane j's u32 holds cols
// c0 = 32*(j&3) + (j>>2) and c0+16 -> two dword stores at the end.
// ---------------------------------------------------------------------------
__global__ __launch_bounds__(256) void gather_out(
    const unsigned short* __restrict__ H, const unsigned* __restrict__ pk2,
    const int* __restrict__ tmp, const int* __restrict__ offs,
    float* __restrict__ out, int n_nodes)
{
    int dst = (blockIdx.x * 256 + threadIdx.x) >> 6;
    const int lane = threadIdx.x & 63;
    if (dst >= n_nodes) return;
    dst = __builtin_amdgcn_readfirstlane(dst);   // wave-uniform by construction

    const unsigned* HH = (const unsigned*)H;
    unsigned u0 = HH[(size_t)dst * 64 + lane];   // root+bias row
    float a0 = bf_lo(u0), a1 = bf_hi(u0);

    const int e0 = tmp[dst] + offs[dst >> 10];
    const int e1 = tmp[dst + 1] + offs[(dst + 1) >> 10];

    for (int base = e0; base < e1; base += 8) {
        float al[8];
        const unsigned* hp[8];
#pragma unroll
        for (int j = 0; j < 8; ++j) {
            int e = base + j;
            bool ok = (e < e1);
            unsigned p = ok ? pk2[e] : 0u;       // uniform address -> s_load
            al[j] = ok ? __builtin_amdgcn_rcpf((float)(p >> 20)) : 0.f;
            hp[j] = HH + (size_t)(p & 0xFFFFFu) * 64;
        }
        unsigned hv[8];
#pragma unroll
        for (int j = 0; j < 8; ++j) hv[j] = hp[j][lane];
#pragma unroll
        for (int j = 0; j < 8; ++j) {
            a0 += al[j] * bf_lo(hv[j]);
            a1 += al[j] * bf_hi(hv[j]);
        }
    }

    const int c0 = ((lane & 3) << 5) + (lane >> 2);
    float* orow = out + (size_t)dst * D;
    orow[c0]      = fmaxf(a0, 0.f);
    orow[c0 + 16] = fmaxf(a1, 0.f);
}

extern "C" void kernel_launch(void* const* d_in, const int* in_sizes, int n_in,
                              void* d_out, int out_size, void* d_ws, size_t ws_size,
                              hipStream_t stream) {
    const float* x          = (const float*)d_in[0];
    const int*   edge_index = (const int*)d_in[1];
    const int*   edge_type  = (const int*)d_in[2];
    const float* W          = (const float*)d_in[3];
    const float* root       = (const float*)d_in[4];
    const float* bias       = (const float*)d_in[5];
    float* out = (float*)d_out;

    const int n_nodes = in_sizes[0] / D;          // 100000
    const int n_edges = in_sizes[2];              // 600000
    const int n_rel   = in_sizes[3] / (D * D);    // 8
    const int nsegs   = n_rel + 1;
    const int nG      = n_nodes * nsegs;          // 900000

    // ws layout (worst-case compact rows = n_nodes + n_edges)
    char* p = (char*)d_ws;
    auto alloc = [&](size_t bytes) {
        char* q = p; p += (bytes + 255) & ~(size_t)255; return q;
    };
    int* c      = (int*)alloc((size_t)n_nodes * n_rel * 4);
    int* G      = (int*)alloc((size_t)(nG + 1) * 4);
    int* tmp    = (int*)alloc((size_t)(nG + 1) * 4);
    int* parts  = (int*)alloc(4096);
    int* offs   = (int*)alloc(4096);
    int* tot    = (int*)alloc(256);
    int* cnt2   = (int*)alloc((size_t)n_nodes * 4);
    unsigned* pk2 = (unsigned*)alloc((size_t)n_edges * 4);
    unsigned* XB  = (unsigned*)alloc((size_t)n_nodes * (D / 2) * 4);
    unsigned short* WT = (unsigned short*)alloc((size_t)nsegs * D * D * 2);
    int* csrc   = (int*)alloc((size_t)n_edges * 4);
    unsigned short* H = (unsigned short*)p;       // worst (n_nodes+n_edges) rows

    const int nquads   = n_nodes * (D / 4);
    const int wt_total = nsegs * D * D;
    int prep_n = nquads;
    if (wt_total > prep_n) prep_n = wt_total;
    if (nG > prep_n) prep_n = nG;

    const int egrid = (n_edges + 255) / 256;
    const int nA = (nG + 1023) / 1024;            // 879 <= 1024

    prep_all<<<(prep_n + 255) / 256, 256, 0, stream>>>(
        x, W, root, XB, WT, c, G, cnt2, nquads, wt_total, n_nodes, n_rel);
    edge_hist<<<egrid, 256, 0, stream>>>(
        edge_index, edge_type, c, G, n_edges, n_nodes, n_rel);
    scanA<<<nA, 1024, 0, stream>>>(G, tmp, parts, nG);
    scanB<<<1, 1024, 0, stream>>>(parts, offs, tot, nA);
    edge_bin<<<egrid, 256, 0, stream>>>(
        edge_index, edge_type, tmp, offs, c, cnt2, pk2, csrc,
        n_edges, n_nodes, n_rel);
    gemm_h<<<1024, 256, 0, stream>>>(
        XB, WT, bias, csrc, tmp, offs, tot, H, n_nodes, n_edges, n_rel);
    gather_out<<<(n_nodes + 3) / 4, 256, 0, stream>>>(
        H, pk2, tmp, offs, out, n_nodes);
}

// Round 2
// 307.191 us; speedup vs baseline: 1.0091x; 1.0091x over previous
//
#include <hip/hip_runtime.h>

// RGCN layer: out[i] = relu( x[i]@root + bias + sum_r mean_{j in N_r(i)} x[j]@W[r] )
//
// Two-phase (linearity) + SOURCE COMPACTION:
//   H rows [0,N) = bf16(x@root + bias); then per rel r one row per USED src:
//   bf16(x[src]@W[r]).  out[i] = relu( H[i] + sum_e (1/c) * H[hidx_e] )
// pk2 packs hidx(20b) | c(8b). gather: wave-uniform dst scalarized.
//
// gemm_h v7: DEEPER SOFTWARE PIPELINE + CHEAP EPILOGUE.
// R15 post-mortem: v6 (no-LDS epilogue) was neutral -> LDS/barrier was never
// the chain. Real chain: csrc load (L2 ~300cy) -> XB 4x16B gather (L3 ~700cy)
// shared only ~350cy of hiding at distance-1, with occupancy capped at
// 2 waves/SIMD (bfr[8][4]=128 regs in AGPRs; VGPR 116 + AGPR ~128).
// v7: (a) csrc prefetched at distance-2, XB at distance-1 -> each leg hides
// under a full tile (~500cy); (b) bias folded into MFMA C-in; (c) epilogue
// pack via v_cvt_pk_bf16_f32 (1 inst/pair vs ~10 manual-RNE ops).
// H row layout (permuted, absorbed by gather_out):
//   u32 index (l16*4 + p) within row = { lo: col 32p+l16, hi: col 32p+l16+16 }

#define D 128

typedef __attribute__((ext_vector_type(8))) short bf16x8;
typedef __attribute__((ext_vector_type(4))) float f32x4;
typedef __attribute__((ext_vector_type(4))) unsigned u32x4;

__device__ inline unsigned short f32_to_bf16(float f) {
    unsigned u = __float_as_uint(f);
    return (unsigned short)((u + 0x7FFF + ((u >> 16) & 1)) >> 16);   // RNE
}
__device__ inline float bf_lo(unsigned u) { return __uint_as_float(u << 16); }
__device__ inline float bf_hi(unsigned u) { return __uint_as_float(u & 0xFFFF0000u); }

// ---------------------------------------------------------------------------
// prep: XB = bf16(x); WT[seg][n][k] = bf16(Wseg[k][n]); zero c, G, cnt2
// ---------------------------------------------------------------------------
__global__ __launch_bounds__(256) void prep_all(
    const float* __restrict__ x, const float* __restrict__ W,
    const float* __restrict__ root,
    unsigned* __restrict__ XB, unsigned short* __restrict__ WT,
    int* __restrict__ c, int* __restrict__ G, int* __restrict__ cnt2,
    int nquads, int wt_total, int n_nodes, int n_rel)
{
    int i = blockIdx.x * 256 + threadIdx.x;
    if (i < nquads) {
        float4 v = ((const float4*)x)[i];
        unsigned w0 = (unsigned)f32_to_bf16(v.x) | ((unsigned)f32_to_bf16(v.y) << 16);
        unsigned w1 = (unsigned)f32_to_bf16(v.z) | ((unsigned)f32_to_bf16(v.w) << 16);
        ((uint2*)XB)[i] = make_uint2(w0, w1);
    }
    if (i < wt_total) {
        int seg = i >> 14, rem = i & 16383;
        int n = rem >> 7, k = rem & 127;
        float v = (seg == 0) ? root[k * D + n]
                             : W[(size_t)(seg - 1) * D * D + k * D + n];
        WT[i] = f32_to_bf16(v);
    }
    if (i < n_nodes * n_rel) c[i] = 0;
    if (i < n_nodes * (n_rel + 1)) G[i] = 0;
    if (i < n_nodes) cnt2[i] = 0;
}

// ---------------------------------------------------------------------------
__global__ __launch_bounds__(256) void edge_hist(
    const int* __restrict__ edge_index, const int* __restrict__ edge_type,
    int* __restrict__ c, int* __restrict__ G, int n_edges, int n_nodes, int n_rel)
{
    int e = blockIdx.x * 256 + threadIdx.x;
    if (e >= n_edges) return;
    int src = edge_index[e];
    int dst = edge_index[n_edges + e];
    int r   = edge_type[e];
    atomicAdd(&c[dst * n_rel + r], 1);
    atomicAdd(&G[dst], 1);                       // degree (CSR)
    G[n_nodes + r * n_nodes + src] = 1;          // used flag (benign race)
}

// ---------------------------------------------------------------------------
// Two-level exclusive scan over G[nG]. Consumers: S(i) = tmp[i] + offs[i>>10].
// ---------------------------------------------------------------------------
__global__ __launch_bounds__(1024) void scanA(
    const int* __restrict__ G, int* __restrict__ tmp, int* __restrict__ parts, int n)
{
    __shared__ int buf[2][1024];
    const int tid = threadIdx.x;
    int i = blockIdx.x * 1024 + tid;
    int v = (i < n) ? G[i] : 0;
    buf[0][tid] = v;
    __syncthreads();
    int pi = 0;
    for (int off = 1; off < 1024; off <<= 1) {
        int t = buf[pi][tid] + ((tid >= off) ? buf[pi][tid - off] : 0);
        buf[1 - pi][tid] = t;
        pi = 1 - pi;
        __syncthreads();
    }
    if (i < n) tmp[i] = buf[pi][tid] - v;
    if (tid == 1023) parts[blockIdx.x] = buf[pi][1023];
}

__global__ __launch_bounds__(1024) void scanB(
    const int* __restrict__ parts, int* __restrict__ offs,
    int* __restrict__ tot, int np)
{
    __shared__ int buf[2][1024];
    const int t = threadIdx.x;
    int v = (t < np) ? parts[t] : 0;
    buf[0][t] = v;
    __syncthreads();
    int pi = 0;
    for (int off = 1; off < 1024; off <<= 1) {
        int s = buf[pi][t] + ((t >= off) ? buf[pi][t - off] : 0);
        buf[1 - pi][t] = s;
        pi = 1 - pi;
        __syncthreads();
    }
    if (t < np) offs[t] = buf[pi][t] - v;
    if (t == 0) tot[0] = buf[pi][1023];          // n_edges + n_compact
}

// ---------------------------------------------------------------------------
// edge_bin: CSR-place each edge; pack hidx|c; build csrc (redundant stores ok)
// ---------------------------------------------------------------------------
__global__ __launch_bounds__(256) void edge_bin(
    const int* __restrict__ edge_index, const int* __restrict__ edge_type,
    const int* __restrict__ tmp, const int* __restrict__ offs,
    const int* __restrict__ c, int* __restrict__ cnt2,
    unsigned* __restrict__ pk2, int* __restrict__ csrc,
    int n_edges, int n_nodes, int n_rel)
{
    int e = blockIdx.x * 256 + threadIdx.x;
    if (e >= n_edges) return;
    int src = edge_index[e];
    int dst = edge_index[n_edges + e];
    int r   = edge_type[e];
    int pos = tmp[dst] + offs[dst >> 10] + atomicAdd(&cnt2[dst], 1);
    int gi  = n_nodes + r * n_nodes + src;
    int cidx = tmp[gi] + offs[gi >> 10] - n_edges;    // compact rel-row index
    int hidx = n_nodes + cidx;                        // < 2^20
    unsigned cc = (unsigned)c[dst * n_rel + r];
    if (cc > 255u) cc = 255u;
    pk2[pos] = (unsigned)hidx | (cc << 20);
    csrc[cidx] = src;                                 // same-value race: benign
}

// ---------------------------------------------------------------------------
// Phase 1 v7: flat-balanced H GEMM, register->global epilogue, 3-stage
// software pipeline: tile t computes while XB(t+1) loads (node index already
// resident from one iteration ago) and csrc(t+2) loads. grid (1024, 1).
// B-frags register/AGPR resident, reloaded only at segment boundaries
// (<=2 per block).
// ---------------------------------------------------------------------------
__global__ __launch_bounds__(256, 2) void gemm_h(
    const unsigned* __restrict__ XB, const unsigned short* __restrict__ WT,
    const float* __restrict__ bias, const int* __restrict__ csrc,
    const int* __restrict__ tmp, const int* __restrict__ offs,
    const int* __restrict__ tot, unsigned short* __restrict__ H,
    int n_nodes, int n_edges, int n_rel)
{
    __shared__ int s_end[9];     // cumulative flat-tile end per seg
    __shared__ int s_cnt[9];     // row count per seg
    __shared__ int s_S0[9];      // csrc base per seg
    __shared__ int s_base[9];    // H base row per seg

    const int tid  = threadIdx.x;
    const int wave = tid >> 6;
    const int lane = tid & 63;
    const int l16  = lane & 15;
    const int quad = lane >> 4;
    const int row_off = wave * 16 + l16;
    const int cq8  = quad * 8;

    if (tid == 0) {
        int acc = 0;
        for (int s = 0; s <= n_rel; ++s) {
            int cnt, S0 = 0, base;
            if (s == 0) { cnt = n_nodes; base = 0; }
            else {
                int r = s - 1;
                int gi0 = n_nodes + r * n_nodes;
                S0 = tmp[gi0] + offs[gi0 >> 10] - n_edges;
                int S1 = (r == n_rel - 1)
                         ? (tot[0] - n_edges)
                         : (tmp[gi0 + n_nodes] + offs[(gi0 + n_nodes) >> 10] - n_edges);
                cnt = S1 - S0;
                base = n_nodes + S0;
            }
            acc += (cnt + 63) >> 6;
            s_end[s] = acc; s_cnt[s] = cnt; s_S0[s] = S0; s_base[s] = base;
        }
    }
    __syncthreads();

    const int nflat = s_end[n_rel];
    const int chunk = (nflat + gridDim.x - 1) / gridDim.x;
    const int ft0 = blockIdx.x * chunk;
    int ft1 = ft0 + chunk; if (ft1 > nflat) ft1 = nflat;
    if (ft0 >= ft1) return;

    auto resolve = [&](int ft, int& seg, int& lt) {
        int s = 0;
        while (ft >= s_end[s]) ++s;
        seg = s;
        lt = ft - (s ? s_end[s - 1] : 0);
    };
    auto load_node = [&](int seg, int lt) -> int {
        int lr = lt * 64 + row_off;
        if (lr >= s_cnt[seg]) return 0;
        return (seg == 0) ? lr : csrc[s_S0[seg] + lr];
    };
    auto load_af = [&](int seg, int lt, int node, bf16x8* fr) {
        int lr = lt * 64 + row_off;
        bool v = (lr < s_cnt[seg]);
        const unsigned short* xr = (const unsigned short*)XB + (size_t)node * D + cq8;
#pragma unroll
        for (int kc = 0; kc < 4; ++kc)
            fr[kc] = v ? *(const bf16x8*)(xr + kc * 32)
                       : (bf16x8){0, 0, 0, 0, 0, 0, 0, 0};
    };

    bf16x8 bfr[8][4];
    float bv[8];
    int cur_seg = -1;

    // ---- pipeline prologue ----
    // state: (segA,ltA) + af     = tile t     (A-frags resident)
    //        (segB,ltB) + nodeB  = tile t+1   (node index resident)
    int segA, ltA;
    resolve(ft0, segA, ltA);
    bf16x8 af[4];
    {
        int nodeA = load_node(segA, ltA);
        load_af(segA, ltA, nodeA, af);
    }
    int segB = 0, ltB = 0, nodeB = 0;
    if (ft0 + 1 < ft1) {
        resolve(ft0 + 1, segB, ltB);
        nodeB = load_node(segB, ltB);
    }

    for (int ft = ft0; ft < ft1; ++ft) {
        const int seg = segA, lt = ltA;
        const bool haveN  = (ft + 1 < ft1);
        const bool haveN2 = (ft + 2 < ft1);

        // stage 3: issue csrc for t+2 (completes during next iteration)
        int segC = 0, ltC = 0, nodeC = 0;
        if (haveN2) {
            resolve(ft + 2, segC, ltC);
            nodeC = load_node(segC, ltC);
        }

        // stage 2: issue XB gathers for t+1 (nodeB loaded one iteration ago)
        bf16x8 afn[4];
        if (haveN) load_af(segB, ltB, nodeB, afn);

        // (re)load B-frags + bias at segment boundary (<=2 per block)
        if (seg != cur_seg) {
            const unsigned short* Wseg = WT + (size_t)seg * D * D;
#pragma unroll
            for (int nt = 0; nt < 8; ++nt) {
                const unsigned short* bp = Wseg + (size_t)(nt * 16 + l16) * D + cq8;
#pragma unroll
                for (int kc = 0; kc < 4; ++kc)
                    bfr[nt][kc] = *(const bf16x8*)(bp + kc * 32);
                bv[nt] = (seg == 0) ? bias[nt * 16 + l16] : 0.f;
            }
            cur_seg = seg;
        }

        // stage 1: compute tile t (bias folded into MFMA C-in; same f32 math)
        f32x4 acc[8];
#pragma unroll
        for (int nt = 0; nt < 8; ++nt) {
            acc[nt] = (f32x4){bv[nt], bv[nt], bv[nt], bv[nt]};
#pragma unroll
            for (int kc = 0; kc < 4; ++kc)
                acc[nt] = __builtin_amdgcn_mfma_f32_16x16x32_bf16(
                    af[kc], bfr[nt][kc], acc[nt], 0, 0, 0);
        }

        // Epilogue: hardware RNE pack (col 32p+l16, col 32p+l16+16) -> u32,
        // one dwordx4 per owned row. Coalesces as 4x256B segments per inst.
        {
            const int rbase = lt * 64 + wave * 16 + quad * 4;
            unsigned short* Hrow =
                H + (size_t)(s_base[seg] + rbase) * D + (size_t)l16 * 8;
#pragma unroll
            for (int reg = 0; reg < 4; ++reg) {
                if (rbase + reg < s_cnt[seg]) {
                    u32x4 w;
#pragma unroll
                    for (int p = 0; p < 4; ++p) {
                        unsigned r;
                        asm("v_cvt_pk_bf16_f32 %0, %1, %2"
                            : "=v"(r)
                            : "v"(acc[2 * p][reg]), "v"(acc[2 * p + 1][reg]));
                        w[p] = r;
                    }
                    *(u32x4*)(Hrow + (size_t)reg * D) = w;
                }
            }
        }

        // rotate pipeline state
        if (haveN) {
            segA = segB; ltA = ltB;
#pragma unroll
            for (int kc = 0; kc < 4; ++kc) af[kc] = afn[kc];
        }
        if (haveN2) { segB = segC; ltB = ltC; nodeB = nodeC; }
    }
}

// ---------------------------------------------------------------------------
// Phase 2: one wave per dst node; dst made explicitly wave-uniform so
// pk2/bounds go through scalar loads; per-lane work = H load + 2 unpack +
// 2 FMA per edge. 1/c via v_rcp (c is a small integer: error ~1 ulp).
// H columns are permuted (see gemm_h): lane j's u32 holds cols
// c0 = 32*(j&3) + (j>>2) and c0+16 -> two dword stores at the end.
// ---------------------------------------------------------------------------
__global__ __launch_bounds__(256) void gather_out(
    const unsigned short* __restrict__ H, const unsigned* __restrict__ pk2,
    const int* __restrict__ tmp, const int* __restrict__ offs,
    float* __restrict__ out, int n_nodes)
{
    int dst = (blockIdx.x * 256 + threadIdx.x) >> 6;
    const int lane = threadIdx.x & 63;
    if (dst >= n_nodes) return;
    dst = __builtin_amdgcn_readfirstlane(dst);   // wave-uniform by construction

    const unsigned* HH = (const unsigned*)H;
    unsigned u0 = HH[(size_t)dst * 64 + lane];   // root+bias row
    float a0 = bf_lo(u0), a1 = bf_hi(u0);

    const int e0 = tmp[dst] + offs[dst >> 10];
    const int e1 = tmp[dst + 1] + offs[(dst + 1) >> 10];

    for (int base = e0; base < e1; base += 8) {
        float al[8];
        const unsigned* hp[8];
#pragma unroll
        for (int j = 0; j < 8; ++j) {
            int e = base + j;
            bool ok = (e < e1);
            unsigned p = ok ? pk2[e] : 0u;       // uniform address -> s_load
            al[j] = ok ? __builtin_amdgcn_rcpf((float)(p >> 20)) : 0.f;
            hp[j] = HH + (size_t)(p & 0xFFFFFu) * 64;
        }
        unsigned hv[8];
#pragma unroll
        for (int j = 0; j < 8; ++j) hv[j] = hp[j][lane];
#pragma unroll
        for (int j = 0; j < 8; ++j) {
            a0 += al[j] * bf_lo(hv[j]);
            a1 += al[j] * bf_hi(hv[j]);
        }
    }

    const int c0 = ((lane & 3) << 5) + (lane >> 2);
    float* orow = out + (size_t)dst * D;
    orow[c0]      = fmaxf(a0, 0.f);
    orow[c0 + 16] = fmaxf(a1, 0.f);
}

extern "C" void kernel_launch(void* const* d_in, const int* in_sizes, int n_in,
                              void* d_out, int out_size, void* d_ws, size_t ws_size,
                              hipStream_t stream) {
    const float* x          = (const float*)d_in[0];
    const int*   edge_index = (const int*)d_in[1];
    const int*   edge_type  = (const int*)d_in[2];
    const float* W          = (const float*)d_in[3];
    const float* root       = (const float*)d_in[4];
    const float* bias       = (const float*)d_in[5];
    float* out = (float*)d_out;

    const int n_nodes = in_sizes[0] / D;          // 100000
    const int n_edges = in_sizes[2];              // 600000
    const int n_rel   = in_sizes[3] / (D * D);    // 8
    const int nsegs   = n_rel + 1;
    const int nG      = n_nodes * nsegs;          // 900000

    // ws layout (worst-case compact rows = n_nodes + n_edges)
    char* p = (char*)d_ws;
    auto alloc = [&](size_t bytes) {
        char* q = p; p += (bytes + 255) & ~(size_t)255; return q;
    };
    int* c      = (int*)alloc((size_t)n_nodes * n_rel * 4);
    int* G      = (int*)alloc((size_t)(nG + 1) * 4);
    int* tmp    = (int*)alloc((size_t)(nG + 1) * 4);
    int* parts  = (int*)alloc(4096);
    int* offs   = (int*)alloc(4096);
    int* tot    = (int*)alloc(256);
    int* cnt2   = (int*)alloc((size_t)n_nodes * 4);
    unsigned* pk2 = (unsigned*)alloc((size_t)n_edges * 4);
    unsigned* XB  = (unsigned*)alloc((size_t)n_nodes * (D / 2) * 4);
    unsigned short* WT = (unsigned short*)alloc((size_t)nsegs * D * D * 2);
    int* csrc   = (int*)alloc((size_t)n_edges * 4);
    unsigned short* H = (unsigned short*)p;       // worst (n_nodes+n_edges) rows

    const int nquads   = n_nodes * (D / 4);
    const int wt_total = nsegs * D * D;
    int prep_n = nquads;
    if (wt_total > prep_n) prep_n = wt_total;
    if (nG > prep_n) prep_n = nG;

    const int egrid = (n_edges + 255) / 256;
    const int nA = (nG + 1023) / 1024;            // 879 <= 1024

    prep_all<<<(prep_n + 255) / 256, 256, 0, stream>>>(
        x, W, root, XB, WT, c, G, cnt2, nquads, wt_total, n_nodes, n_rel);
    edge_hist<<<egrid, 256, 0, stream>>>(
        edge_index, edge_type, c, G, n_edges, n_nodes, n_rel);
    scanA<<<nA, 1024, 0, stream>>>(G, tmp, parts, nG);
    scanB<<<1, 1024, 0, stream>>>(parts, offs, tot, nA);
    edge_bin<<<egrid, 256, 0, stream>>>(
        edge_index, edge_type, tmp, offs, c, cnt2, pk2, csrc,
        n_edges, n_nodes, n_rel);
    gemm_h<<<1024, 256, 0, stream>>>(
        XB, WT, bias, csrc, tmp, offs, tot, H, n_nodes, n_edges, n_rel);
    gather_out<<<(n_nodes + 3) / 4, 256, 0, stream>>>(
        H, pk2, tmp, offs, out, n_nodes);
}

// Round 4
// 283.529 us; speedup vs baseline: 1.0933x; 1.0835x over previous
//
#include <hip/hip_runtime.h>

// RGCN layer: out[i] = relu( x[i]@root + bias + sum_r mean_{j in N_r(i)} x[j]@W[r] )
//
// Two-phase (linearity) + SOURCE COMPACTION:
//   H rows [0,N) = bf16(x@root + bias); then per rel r one row per USED src:
//   bf16(x[src]@W[r]).  out[i] = relu( H[i] + sum_e (1/c) * H[hidx_e] )
// pk2 packs hidx(20b) | r(3b); per-(dst,rel) counts are rebuilt in gather_out
// from the dst's own edge list (scalar pre-pass) -- c[] array, its zeroing,
// its 600k atomics and its 600k random reads all deleted.
//
// R17 (this round): container failed on v8 (distance-2 E/O buffers, +32 VGPR
// over an exactly-full 256-reg budget -> spill risk). De-risked: gemm_h
// reverted to the PROVEN v7 pipeline (61.7us, 128 VGPR, csrc dist-2 /
// XB dist-1, cvt_pk epilogue, bias in MFMA C-in). Kept the register-neutral
// deletions and added the RANK TRICK: prep_hist saves the return of the
// degree atomicAdd as the edge's rank within its dst (sequential store);
// edge_bin uses pos = S(dst)+rank[e] -- its cnt2 atomic (600k contended
// random RMW) is gone, cnt2 deleted.
// H row layout (permuted, absorbed by gather_out):
//   u32 index (l16*4 + p) within row = { lo: col 32p+l16, hi: col 32p+l16+16 }

#define D 128

typedef __attribute__((ext_vector_type(8))) short bf16x8;
typedef __attribute__((ext_vector_type(4))) float f32x4;
typedef __attribute__((ext_vector_type(4))) unsigned u32x4;

__device__ inline unsigned short f32_to_bf16(float f) {
    unsigned u = __float_as_uint(f);
    return (unsigned short)((u + 0x7FFF + ((u >> 16) & 1)) >> 16);   // RNE
}
__device__ inline float bf_lo(unsigned u) { return __uint_as_float(u << 16); }
__device__ inline float bf_hi(unsigned u) { return __uint_as_float(u & 0xFFFF0000u); }

// ---------------------------------------------------------------------------
// zero_ws: G (degree + used-flags) must be zero before hist.
// ---------------------------------------------------------------------------
__global__ __launch_bounds__(256) void zero_ws(
    int* __restrict__ G, int nG)
{
    int i = blockIdx.x * 256 + threadIdx.x;
    if (i < nG + 1) G[i] = 0;
}

// ---------------------------------------------------------------------------
// prep_hist: fused. Blocks [0,hist_blocks) do the edge histogram (atomic
// latency-bound; start first) and record each edge's rank within its dst.
// Blocks [hist_blocks,..) do XB/WT conversion (streaming BW-bound).
// ---------------------------------------------------------------------------
__global__ __launch_bounds__(256) void prep_hist(
    const float* __restrict__ x, const float* __restrict__ W,
    const float* __restrict__ root,
    const int* __restrict__ edge_index, const int* __restrict__ edge_type,
    unsigned* __restrict__ XB, unsigned short* __restrict__ WT,
    int* __restrict__ G, int* __restrict__ erank,
    int nquads, int wt_total, int n_edges, int n_nodes, int n_rel,
    int hist_blocks)
{
    const int b = blockIdx.x;
    if (b < hist_blocks) {
        int e = b * 256 + threadIdx.x;
        if (e >= n_edges) return;
        int src = edge_index[e];
        int dst = edge_index[n_edges + e];
        int r   = edge_type[e];
        erank[e] = atomicAdd(&G[dst], 1);            // degree + rank-in-dst
        G[n_nodes + r * n_nodes + src] = 1;          // used flag (benign race)
        return;
    }
    int i = (b - hist_blocks) * 256 + threadIdx.x;
    if (i < nquads) {
        float4 v = ((const float4*)x)[i];
        unsigned w0 = (unsigned)f32_to_bf16(v.x) | ((unsigned)f32_to_bf16(v.y) << 16);
        unsigned w1 = (unsigned)f32_to_bf16(v.z) | ((unsigned)f32_to_bf16(v.w) << 16);
        ((uint2*)XB)[i] = make_uint2(w0, w1);
    }
    if (i < wt_total) {
        int seg = i >> 14, rem = i & 16383;
        int n = rem >> 7, k = rem & 127;
        float v = (seg == 0) ? root[k * D + n]
                             : W[(size_t)(seg - 1) * D * D + k * D + n];
        WT[i] = f32_to_bf16(v);
    }
}

// ---------------------------------------------------------------------------
// Two-level exclusive scan over G[nG]. Consumers: S(i) = tmp[i] + offs[i>>10].
// ---------------------------------------------------------------------------
__global__ __launch_bounds__(1024) void scanA(
    const int* __restrict__ G, int* __restrict__ tmp, int* __restrict__ parts, int n)
{
    __shared__ int buf[2][1024];
    const int tid = threadIdx.x;
    int i = blockIdx.x * 1024 + tid;
    int v = (i < n) ? G[i] : 0;
    buf[0][tid] = v;
    __syncthreads();
    int pi = 0;
    for (int off = 1; off < 1024; off <<= 1) {
        int t = buf[pi][tid] + ((tid >= off) ? buf[pi][tid - off] : 0);
        buf[1 - pi][tid] = t;
        pi = 1 - pi;
        __syncthreads();
    }
    if (i < n) tmp[i] = buf[pi][tid] - v;
    if (tid == 1023) parts[blockIdx.x] = buf[pi][1023];
}

__global__ __launch_bounds__(1024) void scanB(
    const int* __restrict__ parts, int* __restrict__ offs,
    int* __restrict__ tot, int np)
{
    __shared__ int buf[2][1024];
    const int t = threadIdx.x;
    int v = (t < np) ? parts[t] : 0;
    buf[0][t] = v;
    __syncthreads();
    int pi = 0;
    for (int off = 1; off < 1024; off <<= 1) {
        int s = buf[pi][t] + ((t >= off) ? buf[pi][t - off] : 0);
        buf[1 - pi][t] = s;
        pi = 1 - pi;
        __syncthreads();
    }
    if (t < np) offs[t] = buf[pi][t] - v;
    if (t == 0) tot[0] = buf[pi][1023];          // n_edges + n_compact
}

// ---------------------------------------------------------------------------
// edge_bin: CSR-place each edge at S(dst)+rank (no atomics); pack hidx|r;
// build csrc (redundant same-value stores: benign)
// ---------------------------------------------------------------------------
__global__ __launch_bounds__(256) void edge_bin(
    const int* __restrict__ edge_index, const int* __restrict__ edge_type,
    const int* __restrict__ tmp, const int* __restrict__ offs,
    const int* __restrict__ erank,
    unsigned* __restrict__ pk2, int* __restrict__ csrc,
    int n_edges, int n_nodes, int n_rel)
{
    int e = blockIdx.x * 256 + threadIdx.x;
    if (e >= n_edges) return;
    int src = edge_index[e];
    int dst = edge_index[n_edges + e];
    int r   = edge_type[e];
    int pos = tmp[dst] + offs[dst >> 10] + erank[e];
    int gi  = n_nodes + r * n_nodes + src;
    int cidx = tmp[gi] + offs[gi >> 10] - n_edges;    // compact rel-row index
    int hidx = n_nodes + cidx;                        // < 2^20
    pk2[pos] = (unsigned)hidx | ((unsigned)r << 20);
    csrc[cidx] = src;                                 // same-value race: benign
}

// ---------------------------------------------------------------------------
// Phase 1 (v7 pipeline, proven): flat-balanced H GEMM, register->global
// epilogue, 3-stage software pipeline: tile t computes while XB(t+1) loads
// (node index already resident from one iteration ago) and csrc(t+2) loads.
// grid (1024, 1). B-frags register/AGPR resident, reloaded only at segment
// boundaries (<=2 per block). 128 VGPR + ~128 AGPR = exactly the 2-waves/SIMD
// budget -- do NOT add live registers to this loop (R17: +32 broke it).
// ---------------------------------------------------------------------------
__global__ __launch_bounds__(256, 2) void gemm_h(
    const unsigned* __restrict__ XB, const unsigned short* __restrict__ WT,
    const float* __restrict__ bias, const int* __restrict__ csrc,
    const int* __restrict__ tmp, const int* __restrict__ offs,
    const int* __restrict__ tot, unsigned short* __restrict__ H,
    int n_nodes, int n_edges, int n_rel)
{
    __shared__ int s_end[9];     // cumulative flat-tile end per seg
    __shared__ int s_cnt[9];     // row count per seg
    __shared__ int s_S0[9];      // csrc base per seg
    __shared__ int s_base[9];    // H base row per seg

    const int tid  = threadIdx.x;
    const int wave = tid >> 6;
    const int lane = tid & 63;
    const int l16  = lane & 15;
    const int quad = lane >> 4;
    const int row_off = wave * 16 + l16;
    const int cq8  = quad * 8;

    if (tid == 0) {
        int acc = 0;
        for (int s = 0; s <= n_rel; ++s) {
            int cnt, S0 = 0, base;
            if (s == 0) { cnt = n_nodes; base = 0; }
            else {
                int r = s - 1;
                int gi0 = n_nodes + r * n_nodes;
                S0 = tmp[gi0] + offs[gi0 >> 10] - n_edges;
                int S1 = (r == n_rel - 1)
                         ? (tot[0] - n_edges)
                         : (tmp[gi0 + n_nodes] + offs[(gi0 + n_nodes) >> 10] - n_edges);
                cnt = S1 - S0;
                base = n_nodes + S0;
            }
            acc += (cnt + 63) >> 6;
            s_end[s] = acc; s_cnt[s] = cnt; s_S0[s] = S0; s_base[s] = base;
        }
    }
    __syncthreads();

    const int nflat = s_end[n_rel];
    const int chunk = (nflat + gridDim.x - 1) / gridDim.x;
    const int ft0 = blockIdx.x * chunk;
    int ft1 = ft0 + chunk; if (ft1 > nflat) ft1 = nflat;
    if (ft0 >= ft1) return;

    auto resolve = [&](int ft, int& seg, int& lt) {
        int s = 0;
        while (ft >= s_end[s]) ++s;
        seg = s;
        lt = ft - (s ? s_end[s - 1] : 0);
    };
    auto load_node = [&](int seg, int lt) -> int {
        int lr = lt * 64 + row_off;
        if (lr >= s_cnt[seg]) return 0;
        return (seg == 0) ? lr : csrc[s_S0[seg] + lr];
    };
    auto load_af = [&](int seg, int lt, int node, bf16x8* fr) {
        int lr = lt * 64 + row_off;
        bool v = (lr < s_cnt[seg]);
        const unsigned short* xr = (const unsigned short*)XB + (size_t)node * D + cq8;
#pragma unroll
        for (int kc = 0; kc < 4; ++kc)
            fr[kc] = v ? *(const bf16x8*)(xr + kc * 32)
                       : (bf16x8){0, 0, 0, 0, 0, 0, 0, 0};
    };

    bf16x8 bfr[8][4];
    float bv[8];
    int cur_seg = -1;

    // ---- pipeline prologue ----
    // state: (segA,ltA) + af     = tile t     (A-frags resident)
    //        (segB,ltB) + nodeB  = tile t+1   (node index resident)
    int segA, ltA;
    resolve(ft0, segA, ltA);
    bf16x8 af[4];
    {
        int nodeA = load_node(segA, ltA);
        load_af(segA, ltA, nodeA, af);
    }
    int segB = 0, ltB = 0, nodeB = 0;
    if (ft0 + 1 < ft1) {
        resolve(ft0 + 1, segB, ltB);
        nodeB = load_node(segB, ltB);
    }

    for (int ft = ft0; ft < ft1; ++ft) {
        const int seg = segA, lt = ltA;
        const bool haveN  = (ft + 1 < ft1);
        const bool haveN2 = (ft + 2 < ft1);

        // stage 3: issue csrc for t+2 (completes during next iteration)
        int segC = 0, ltC = 0, nodeC = 0;
        if (haveN2) {
            resolve(ft + 2, segC, ltC);
            nodeC = load_node(segC, ltC);
        }

        // stage 2: issue XB gathers for t+1 (nodeB loaded one iteration ago)
        bf16x8 afn[4];
        if (haveN) load_af(segB, ltB, nodeB, afn);

        // (re)load B-frags + bias at segment boundary (<=2 per block)
        if (seg != cur_seg) {
            const unsigned short* Wseg = WT + (size_t)seg * D * D;
#pragma unroll
            for (int nt = 0; nt < 8; ++nt) {
                const unsigned short* bp = Wseg + (size_t)(nt * 16 + l16) * D + cq8;
#pragma unroll
                for (int kc = 0; kc < 4; ++kc)
                    bfr[nt][kc] = *(const bf16x8*)(bp + kc * 32);
                bv[nt] = (seg == 0) ? bias[nt * 16 + l16] : 0.f;
            }
            cur_seg = seg;
        }

        // stage 1: compute tile t (bias folded into MFMA C-in; same f32 math)
        f32x4 acc[8];
#pragma unroll
        for (int nt = 0; nt < 8; ++nt) {
            acc[nt] = (f32x4){bv[nt], bv[nt], bv[nt], bv[nt]};
#pragma unroll
            for (int kc = 0; kc < 4; ++kc)
                acc[nt] = __builtin_amdgcn_mfma_f32_16x16x32_bf16(
                    af[kc], bfr[nt][kc], acc[nt], 0, 0, 0);
        }

        // Epilogue: hardware RNE pack (col 32p+l16, col 32p+l16+16) -> u32,
        // one dwordx4 per owned row. Coalesces as 4x256B segments per inst.
        {
            const int rbase = lt * 64 + wave * 16 + quad * 4;
            unsigned short* Hrow =
                H + (size_t)(s_base[seg] + rbase) * D + (size_t)l16 * 8;
#pragma unroll
            for (int reg = 0; reg < 4; ++reg) {
                if (rbase + reg < s_cnt[seg]) {
                    u32x4 w;
#pragma unroll
                    for (int p = 0; p < 4; ++p) {
                        unsigned r;
                        asm("v_cvt_pk_bf16_f32 %0, %1, %2"
                            : "=v"(r)
                            : "v"(acc[2 * p][reg]), "v"(acc[2 * p + 1][reg]));
                        w[p] = r;
                    }
                    *(u32x4*)(Hrow + (size_t)reg * D) = w;
                }
            }
        }

        // rotate pipeline state
        if (haveN) {
            segA = segB; ltA = ltB;
#pragma unroll
            for (int kc = 0; kc < 4; ++kc) af[kc] = afn[kc];
        }
        if (haveN2) { segB = segC; ltB = ltC; nodeB = nodeC; }
    }
}

// ---------------------------------------------------------------------------
// Phase 2: one wave per dst node; dst made explicitly wave-uniform so
// pk2/bounds go through scalar loads; per-lane work = H load + 2 unpack +
// 2 FMA per edge. Per-(dst,rel) counts rebuilt here from the dst's edge list
// (scalar pre-pass, two packed u32 accumulators with 8-bit fields). 1/c via
// v_rcp (c is a small integer: error ~1 ulp).
// H columns are permuted (see gemm_h): lane j's u32 holds cols
// c0 = 32*(j&3) + (j>>2) and c0+16 -> two dword stores at the end.
// ---------------------------------------------------------------------------
__global__ __launch_bounds__(256) void gather_out(
    const unsigned short* __restrict__ H, const unsigned* __restrict__ pk2,
    const int* __restrict__ tmp, const int* __restrict__ offs,
    float* __restrict__ out, int n_nodes)
{
    int dst = (blockIdx.x * 256 + threadIdx.x) >> 6;
    const int lane = threadIdx.x & 63;
    if (dst >= n_nodes) return;
    dst = __builtin_amdgcn_readfirstlane(dst);   // wave-uniform by construction

    const unsigned* HH = (const unsigned*)H;
    unsigned u0 = HH[(size_t)dst * 64 + lane];   // root+bias row
    float a0 = bf_lo(u0), a1 = bf_hi(u0);

    const int e0 = tmp[dst] + offs[dst >> 10];
    const int e1 = tmp[dst + 1] + offs[(dst + 1) >> 10];

    // scalar pre-pass: per-rel counts (8x 8-bit fields in two u32s)
    unsigned acc0 = 0, acc1 = 0;
    for (int e = e0; e < e1; ++e) {
        unsigned p = pk2[e];                     // uniform -> s_load, L1-hot
        unsigned r = (p >> 20) & 7u;
        unsigned add = 1u << ((r & 3u) * 8u);
        if (r & 4u) acc1 += add; else acc0 += add;
    }

    for (int base = e0; base < e1; base += 8) {
        float al[8];
        const unsigned* hp[8];
#pragma unroll
        for (int j = 0; j < 8; ++j) {
            int e = base + j;
            bool ok = (e < e1);
            unsigned p = ok ? pk2[e] : 0u;       // uniform address -> s_load
            unsigned r = (p >> 20) & 7u;
            unsigned cnt = (((r & 4u) ? acc1 : acc0) >> ((r & 3u) * 8u)) & 255u;
            al[j] = ok ? __builtin_amdgcn_rcpf((float)cnt) : 0.f;
            hp[j] = HH + (size_t)(p & 0xFFFFFu) * 64;
        }
        unsigned hv[8];
#pragma unroll
        for (int j = 0; j < 8; ++j) hv[j] = hp[j][lane];
#pragma unroll
        for (int j = 0; j < 8; ++j) {
            a0 += al[j] * bf_lo(hv[j]);
            a1 += al[j] * bf_hi(hv[j]);
        }
    }

    const int c0 = ((lane & 3) << 5) + (lane >> 2);
    float* orow = out + (size_t)dst * D;
    orow[c0]      = fmaxf(a0, 0.f);
    orow[c0 + 16] = fmaxf(a1, 0.f);
}

extern "C" void kernel_launch(void* const* d_in, const int* in_sizes, int n_in,
                              void* d_out, int out_size, void* d_ws, size_t ws_size,
                              hipStream_t stream) {
    const float* x          = (const float*)d_in[0];
    const int*   edge_index = (const int*)d_in[1];
    const int*   edge_type  = (const int*)d_in[2];
    const float* W          = (const float*)d_in[3];
    const float* root       = (const float*)d_in[4];
    const float* bias       = (const float*)d_in[5];
    float* out = (float*)d_out;

    const int n_nodes = in_sizes[0] / D;          // 100000
    const int n_edges = in_sizes[2];              // 600000
    const int n_rel   = in_sizes[3] / (D * D);    // 8
    const int nsegs   = n_rel + 1;
    const int nG      = n_nodes * nsegs;          // 900000

    // ws layout (worst-case compact rows = n_nodes + n_edges)
    char* p = (char*)d_ws;
    auto alloc = [&](size_t bytes) {
        char* q = p; p += (bytes + 255) & ~(size_t)255; return q;
    };
    int* G      = (int*)alloc((size_t)(nG + 1) * 4);
    int* tmp    = (int*)alloc((size_t)(nG + 1) * 4);
    int* parts  = (int*)alloc(4096);
    int* offs   = (int*)alloc(4096);
    int* tot    = (int*)alloc(256);
    int* erank  = (int*)alloc((size_t)n_edges * 4);
    unsigned* pk2 = (unsigned*)alloc((size_t)n_edges * 4);
    unsigned* XB  = (unsigned*)alloc((size_t)n_nodes * (D / 2) * 4);
    unsigned short* WT = (unsigned short*)alloc((size_t)nsegs * D * D * 2);
    int* csrc   = (int*)alloc((size_t)n_edges * 4);
    unsigned short* H = (unsigned short*)p;       // worst (n_nodes+n_edges) rows

    const int nquads   = n_nodes * (D / 4);
    const int wt_total = nsegs * D * D;
    int conv_n = nquads;
    if (wt_total > conv_n) conv_n = wt_total;

    const int egrid = (n_edges + 255) / 256;
    const int conv_blocks = (conv_n + 255) / 256;
    const int nA = (nG + 1023) / 1024;            // 879 <= 1024

    zero_ws<<<(nG + 1 + 255) / 256, 256, 0, stream>>>(G, nG);
    prep_hist<<<egrid + conv_blocks, 256, 0, stream>>>(
        x, W, root, edge_index, edge_type, XB, WT, G, erank,
        nquads, wt_total, n_edges, n_nodes, n_rel, egrid);
    scanA<<<nA, 1024, 0, stream>>>(G, tmp, parts, nG);
    scanB<<<1, 1024, 0, stream>>>(parts, offs, tot, nA);
    edge_bin<<<egrid, 256, 0, stream>>>(
        edge_index, edge_type, tmp, offs, erank, pk2, csrc,
        n_edges, n_nodes, n_rel);
    gemm_h<<<1024, 256, 0, stream>>>(
        XB, WT, bias, csrc, tmp, offs, tot, H, n_nodes, n_edges, n_rel);
    gather_out<<<(n_nodes + 3) / 4, 256, 0, stream>>>(
        H, pk2, tmp, offs, out, n_nodes);
}

// Round 5
// 267.373 us; speedup vs baseline: 1.1593x; 1.0604x over previous
//
#include <hip/hip_runtime.h>

// RGCN layer: out[i] = relu( x[i]@root + bias + sum_r mean_{j in N_r(i)} x[j]@W[r] )
//
// Two-phase (linearity) + SOURCE COMPACTION:
//   H rows [0,N) = bf16(x@root + bias); then per rel r one row per USED src:
//   bf16(x[src]@W[r]).  out[i] = relu( H[i] + sum_e (1/c) * H[hidx_e] )
// pk2 packs hidx(20b) | r(3b); per-(dst,rel) counts are rebuilt in gather_out
// from the dst's own edge list -- R18: via wave-parallel BALLOT histogram
// (one coalesced pk2 vector load + 8 ballots) instead of a serial scalar
// pre-pass (degree x ~200cy dependent s_load chain).
//
// gemm_h (v7 pipeline, proven 61.7us; R17: do NOT add live registers --
// 128 VGPR + ~128 AGPR is exactly the 2-waves/SIMD budget).
// R18: grid 1024->512 (8 -> 16 iters/block; prologue [segment table ~1.8kcy
// serial + B-fill ~700cy + first gather ~900cy] amortized 2x; 512 blocks =
// exactly 2 resident blocks/CU, so no occupancy loss) and the segment-table
// setup parallelized across 9 threads (two cheap barriers replace the
// tid==0 serial chain of ~18 dependent L2 loads).
// H row layout (permuted, absorbed by gather_out):
//   u32 index (l16*4 + p) within row = { lo: col 32p+l16, hi: col 32p+l16+16 }

#define D 128

typedef __attribute__((ext_vector_type(8))) short bf16x8;
typedef __attribute__((ext_vector_type(4))) float f32x4;
typedef __attribute__((ext_vector_type(4))) unsigned u32x4;

__device__ inline unsigned short f32_to_bf16(float f) {
    unsigned u = __float_as_uint(f);
    return (unsigned short)((u + 0x7FFF + ((u >> 16) & 1)) >> 16);   // RNE
}
__device__ inline float bf_lo(unsigned u) { return __uint_as_float(u << 16); }
__device__ inline float bf_hi(unsigned u) { return __uint_as_float(u & 0xFFFF0000u); }

// ---------------------------------------------------------------------------
// zero_ws: G (degree + used-flags) must be zero before hist.
// ---------------------------------------------------------------------------
__global__ __launch_bounds__(256) void zero_ws(
    int* __restrict__ G, int nG)
{
    int i = blockIdx.x * 256 + threadIdx.x;
    if (i < nG + 1) G[i] = 0;
}

// ---------------------------------------------------------------------------
// prep_hist: fused. Blocks [0,hist_blocks) do the edge histogram (atomic
// latency-bound; start first) and record each edge's rank within its dst.
// Blocks [hist_blocks,..) do XB/WT conversion (streaming BW-bound).
// ---------------------------------------------------------------------------
__global__ __launch_bounds__(256) void prep_hist(
    const float* __restrict__ x, const float* __restrict__ W,
    const float* __restrict__ root,
    const int* __restrict__ edge_index, const int* __restrict__ edge_type,
    unsigned* __restrict__ XB, unsigned short* __restrict__ WT,
    int* __restrict__ G, int* __restrict__ erank,
    int nquads, int wt_total, int n_edges, int n_nodes, int n_rel,
    int hist_blocks)
{
    const int b = blockIdx.x;
    if (b < hist_blocks) {
        int e = b * 256 + threadIdx.x;
        if (e >= n_edges) return;
        int src = edge_index[e];
        int dst = edge_index[n_edges + e];
        int r   = edge_type[e];
        erank[e] = atomicAdd(&G[dst], 1);            // degree + rank-in-dst
        G[n_nodes + r * n_nodes + src] = 1;          // used flag (benign race)
        return;
    }
    int i = (b - hist_blocks) * 256 + threadIdx.x;
    if (i < nquads) {
        float4 v = ((const float4*)x)[i];
        unsigned w0 = (unsigned)f32_to_bf16(v.x) | ((unsigned)f32_to_bf16(v.y) << 16);
        unsigned w1 = (unsigned)f32_to_bf16(v.z) | ((unsigned)f32_to_bf16(v.w) << 16);
        ((uint2*)XB)[i] = make_uint2(w0, w1);
    }
    if (i < wt_total) {
        int seg = i >> 14, rem = i & 16383;
        int n = rem >> 7, k = rem & 127;
        float v = (seg == 0) ? root[k * D + n]
                             : W[(size_t)(seg - 1) * D * D + k * D + n];
        WT[i] = f32_to_bf16(v);
    }
}

// ---------------------------------------------------------------------------
// Two-level exclusive scan over G[nG]. Consumers: S(i) = tmp[i] + offs[i>>10].
// ---------------------------------------------------------------------------
__global__ __launch_bounds__(1024) void scanA(
    const int* __restrict__ G, int* __restrict__ tmp, int* __restrict__ parts, int n)
{
    __shared__ int buf[2][1024];
    const int tid = threadIdx.x;
    int i = blockIdx.x * 1024 + tid;
    int v = (i < n) ? G[i] : 0;
    buf[0][tid] = v;
    __syncthreads();
    int pi = 0;
    for (int off = 1; off < 1024; off <<= 1) {
        int t = buf[pi][tid] + ((tid >= off) ? buf[pi][tid - off] : 0);
        buf[1 - pi][tid] = t;
        pi = 1 - pi;
        __syncthreads();
    }
    if (i < n) tmp[i] = buf[pi][tid] - v;
    if (tid == 1023) parts[blockIdx.x] = buf[pi][1023];
}

__global__ __launch_bounds__(1024) void scanB(
    const int* __restrict__ parts, int* __restrict__ offs,
    int* __restrict__ tot, int np)
{
    __shared__ int buf[2][1024];
    const int t = threadIdx.x;
    int v = (t < np) ? parts[t] : 0;
    buf[0][t] = v;
    __syncthreads();
    int pi = 0;
    for (int off = 1; off < 1024; off <<= 1) {
        int s = buf[pi][t] + ((t >= off) ? buf[pi][t - off] : 0);
        buf[1 - pi][t] = s;
        pi = 1 - pi;
        __syncthreads();
    }
    if (t < np) offs[t] = buf[pi][t] - v;
    if (t == 0) tot[0] = buf[pi][1023];          // n_edges + n_compact
}

// ---------------------------------------------------------------------------
// edge_bin: CSR-place each edge at S(dst)+rank (no atomics); pack hidx|r;
// build csrc (redundant same-value stores: benign)
// ---------------------------------------------------------------------------
__global__ __launch_bounds__(256) void edge_bin(
    const int* __restrict__ edge_index, const int* __restrict__ edge_type,
    const int* __restrict__ tmp, const int* __restrict__ offs,
    const int* __restrict__ erank,
    unsigned* __restrict__ pk2, int* __restrict__ csrc,
    int n_edges, int n_nodes, int n_rel)
{
    int e = blockIdx.x * 256 + threadIdx.x;
    if (e >= n_edges) return;
    int src = edge_index[e];
    int dst = edge_index[n_edges + e];
    int r   = edge_type[e];
    int pos = tmp[dst] + offs[dst >> 10] + erank[e];
    int gi  = n_nodes + r * n_nodes + src;
    int cidx = tmp[gi] + offs[gi >> 10] - n_edges;    // compact rel-row index
    int hidx = n_nodes + cidx;                        // < 2^20
    pk2[pos] = (unsigned)hidx | ((unsigned)r << 20);
    csrc[cidx] = src;                                 // same-value race: benign
}

// ---------------------------------------------------------------------------
// Phase 1 (v7 pipeline, proven): flat-balanced H GEMM, register->global
// epilogue, 3-stage software pipeline: tile t computes while XB(t+1) loads
// (node index already resident from one iteration ago) and csrc(t+2) loads.
// grid (512, 1) -- 16 iters/block, 2 resident blocks/CU. Segment table built
// by 9 threads in parallel. B-frags register/AGPR resident, reloaded only at
// segment boundaries (<=2 per block). 128 VGPR + ~128 AGPR = exactly the
// 2-waves/SIMD budget -- do NOT add live registers to this loop.
// ---------------------------------------------------------------------------
__global__ __launch_bounds__(256, 2) void gemm_h(
    const unsigned* __restrict__ XB, const unsigned short* __restrict__ WT,
    const float* __restrict__ bias, const int* __restrict__ csrc,
    const int* __restrict__ tmp, const int* __restrict__ offs,
    const int* __restrict__ tot, unsigned short* __restrict__ H,
    int n_nodes, int n_edges, int n_rel)
{
    __shared__ int s_end[9];     // cumulative flat-tile end per seg
    __shared__ int s_cnt[9];     // row count per seg
    __shared__ int s_S0[9];      // csrc base per seg
    __shared__ int s_base[9];    // H base row per seg

    const int tid  = threadIdx.x;
    const int wave = tid >> 6;
    const int lane = tid & 63;
    const int l16  = lane & 15;
    const int quad = lane >> 4;
    const int row_off = wave * 16 + l16;
    const int cq8  = quad * 8;

    // segment table: 9 threads in parallel (each ~2 independent L2 loads),
    // then a 9-element prefix by thread 0 (LDS-local, fast).
    if (tid <= n_rel) {
        const int s = tid;
        int cnt, S0 = 0, base;
        if (s == 0) { cnt = n_nodes; base = 0; }
        else {
            int r = s - 1;
            int gi0 = n_nodes + r * n_nodes;
            S0 = tmp[gi0] + offs[gi0 >> 10] - n_edges;
            int S1 = (r == n_rel - 1)
                     ? (tot[0] - n_edges)
                     : (tmp[gi0 + n_nodes] + offs[(gi0 + n_nodes) >> 10] - n_edges);
            cnt = S1 - S0;
            base = n_nodes + S0;
        }
        s_cnt[s] = cnt; s_S0[s] = S0; s_base[s] = base;
        s_end[s] = (cnt + 63) >> 6;              // per-seg tile count (pre-prefix)
    }
    __syncthreads();
    if (tid == 0) {
        int acc = 0;
        for (int s = 0; s <= n_rel; ++s) { acc += s_end[s]; s_end[s] = acc; }
    }
    __syncthreads();

    const int nflat = s_end[n_rel];
    const int chunk = (nflat + gridDim.x - 1) / gridDim.x;
    const int ft0 = blockIdx.x * chunk;
    int ft1 = ft0 + chunk; if (ft1 > nflat) ft1 = nflat;
    if (ft0 >= ft1) return;

    auto resolve = [&](int ft, int& seg, int& lt) {
        int s = 0;
        while (ft >= s_end[s]) ++s;
        seg = s;
        lt = ft - (s ? s_end[s - 1] : 0);
    };
    auto load_node = [&](int seg, int lt) -> int {
        int lr = lt * 64 + row_off;
        if (lr >= s_cnt[seg]) return 0;
        return (seg == 0) ? lr : csrc[s_S0[seg] + lr];
    };
    auto load_af = [&](int seg, int lt, int node, bf16x8* fr) {
        int lr = lt * 64 + row_off;
        bool v = (lr < s_cnt[seg]);
        const unsigned short* xr = (const unsigned short*)XB + (size_t)node * D + cq8;
#pragma unroll
        for (int kc = 0; kc < 4; ++kc)
            fr[kc] = v ? *(const bf16x8*)(xr + kc * 32)
                       : (bf16x8){0, 0, 0, 0, 0, 0, 0, 0};
    };

    bf16x8 bfr[8][4];
    float bv[8];
    int cur_seg = -1;

    // ---- pipeline prologue ----
    // state: (segA,ltA) + af     = tile t     (A-frags resident)
    //        (segB,ltB) + nodeB  = tile t+1   (node index resident)
    int segA, ltA;
    resolve(ft0, segA, ltA);
    bf16x8 af[4];
    {
        int nodeA = load_node(segA, ltA);
        load_af(segA, ltA, nodeA, af);
    }
    int segB = 0, ltB = 0, nodeB = 0;
    if (ft0 + 1 < ft1) {
        resolve(ft0 + 1, segB, ltB);
        nodeB = load_node(segB, ltB);
    }

    for (int ft = ft0; ft < ft1; ++ft) {
        const int seg = segA, lt = ltA;
        const bool haveN  = (ft + 1 < ft1);
        const bool haveN2 = (ft + 2 < ft1);

        // stage 3: issue csrc for t+2 (completes during next iteration)
        int segC = 0, ltC = 0, nodeC = 0;
        if (haveN2) {
            resolve(ft + 2, segC, ltC);
            nodeC = load_node(segC, ltC);
        }

        // stage 2: issue XB gathers for t+1 (nodeB loaded one iteration ago)
        bf16x8 afn[4];
        if (haveN) load_af(segB, ltB, nodeB, afn);

        // (re)load B-frags + bias at segment boundary (<=2 per block)
        if (seg != cur_seg) {
            const unsigned short* Wseg = WT + (size_t)seg * D * D;
#pragma unroll
            for (int nt = 0; nt < 8; ++nt) {
                const unsigned short* bp = Wseg + (size_t)(nt * 16 + l16) * D + cq8;
#pragma unroll
                for (int kc = 0; kc < 4; ++kc)
                    bfr[nt][kc] = *(const bf16x8*)(bp + kc * 32);
                bv[nt] = (seg == 0) ? bias[nt * 16 + l16] : 0.f;
            }
            cur_seg = seg;
        }

        // stage 1: compute tile t (bias folded into MFMA C-in; same f32 math)
        f32x4 acc[8];
#pragma unroll
        for (int nt = 0; nt < 8; ++nt) {
            acc[nt] = (f32x4){bv[nt], bv[nt], bv[nt], bv[nt]};
#pragma unroll
            for (int kc = 0; kc < 4; ++kc)
                acc[nt] = __builtin_amdgcn_mfma_f32_16x16x32_bf16(
                    af[kc], bfr[nt][kc], acc[nt], 0, 0, 0);
        }

        // Epilogue: hardware RNE pack (col 32p+l16, col 32p+l16+16) -> u32,
        // one dwordx4 per owned row. Coalesces as 4x256B segments per inst.
        {
            const int rbase = lt * 64 + wave * 16 + quad * 4;
            unsigned short* Hrow =
                H + (size_t)(s_base[seg] + rbase) * D + (size_t)l16 * 8;
#pragma unroll
            for (int reg = 0; reg < 4; ++reg) {
                if (rbase + reg < s_cnt[seg]) {
                    u32x4 w;
#pragma unroll
                    for (int p = 0; p < 4; ++p) {
                        unsigned r;
                        asm("v_cvt_pk_bf16_f32 %0, %1, %2"
                            : "=v"(r)
                            : "v"(acc[2 * p][reg]), "v"(acc[2 * p + 1][reg]));
                        w[p] = r;
                    }
                    *(u32x4*)(Hrow + (size_t)reg * D) = w;
                }
            }
        }

        // rotate pipeline state
        if (haveN) {
            segA = segB; ltA = ltB;
#pragma unroll
            for (int kc = 0; kc < 4; ++kc) af[kc] = afn[kc];
        }
        if (haveN2) { segB = segC; ltB = ltC; nodeB = nodeC; }
    }
}

// ---------------------------------------------------------------------------
// Phase 2: one wave per dst node; dst made explicitly wave-uniform so
// pk2/bounds go through scalar loads; per-lane work = H load + 2 unpack +
// 2 FMA per edge. Per-(dst,rel) counts via wave-parallel ballot histogram
// (R18): one coalesced pk2 vector load, 8 ballots+popcounts -> packed 8-bit
// fields in two u32s (scalar fallback for degree > 64, ~never). 1/c via
// v_rcp (c is a small integer: error ~1 ulp).
// H columns are permuted (see gemm_h): lane j's u32 holds cols
// c0 = 32*(j&3) + (j>>2) and c0+16 -> two dword stores at the end.
// ---------------------------------------------------------------------------
__global__ __launch_bounds__(256) void gather_out(
    const unsigned short* __restrict__ H, const unsigned* __restrict__ pk2,
    const int* __restrict__ tmp, const int* __restrict__ offs,
    float* __restrict__ out, int n_nodes)
{
    int dst = (blockIdx.x * 256 + threadIdx.x) >> 6;
    const int lane = threadIdx.x & 63;
    if (dst >= n_nodes) return;
    dst = __builtin_amdgcn_readfirstlane(dst);   // wave-uniform by construction

    const unsigned* HH = (const unsigned*)H;
    unsigned u0 = HH[(size_t)dst * 64 + lane];   // root+bias row
    float a0 = bf_lo(u0), a1 = bf_hi(u0);

    const int e0 = tmp[dst] + offs[dst >> 10];
    const int e1 = tmp[dst + 1] + offs[(dst + 1) >> 10];
    const int d  = e1 - e0;

    // per-rel counts (8x 8-bit fields in two u32s)
    unsigned acc0 = 0, acc1 = 0;
    if (d <= 64) {
        // wave-parallel: one coalesced vector load + 8 ballots
        const bool valid = lane < d;
        unsigned p = valid ? pk2[e0 + lane] : 0u;
        unsigned r = (p >> 20) & 7u;
#pragma unroll
        for (int rr = 0; rr < 8; ++rr) {
            unsigned long long m = __ballot(valid && (r == (unsigned)rr));
            unsigned cnt = (unsigned)__popcll(m);
            if (rr < 4) acc0 |= cnt << (rr * 8);
            else        acc1 |= cnt << ((rr - 4) * 8);
        }
    } else {
        // rare fallback: scalar pre-pass
        for (int e = e0; e < e1; ++e) {
            unsigned p = pk2[e];
            unsigned r = (p >> 20) & 7u;
            unsigned add = 1u << ((r & 3u) * 8u);
            if (r & 4u) acc1 += add; else acc0 += add;
        }
    }

    for (int base = e0; base < e1; base += 8) {
        float al[8];
        const unsigned* hp[8];
#pragma unroll
        for (int j = 0; j < 8; ++j) {
            int e = base + j;
            bool ok = (e < e1);
            unsigned p = ok ? pk2[e] : 0u;       // uniform address -> s_load
            unsigned r = (p >> 20) & 7u;
            unsigned cnt = (((r & 4u) ? acc1 : acc0) >> ((r & 3u) * 8u)) & 255u;
            al[j] = ok ? __builtin_amdgcn_rcpf((float)cnt) : 0.f;
            hp[j] = HH + (size_t)(p & 0xFFFFFu) * 64;
        }
        unsigned hv[8];
#pragma unroll
        for (int j = 0; j < 8; ++j) hv[j] = hp[j][lane];
#pragma unroll
        for (int j = 0; j < 8; ++j) {
            a0 += al[j] * bf_lo(hv[j]);
            a1 += al[j] * bf_hi(hv[j]);
        }
    }

    const int c0 = ((lane & 3) << 5) + (lane >> 2);
    float* orow = out + (size_t)dst * D;
    orow[c0]      = fmaxf(a0, 0.f);
    orow[c0 + 16] = fmaxf(a1, 0.f);
}

extern "C" void kernel_launch(void* const* d_in, const int* in_sizes, int n_in,
                              void* d_out, int out_size, void* d_ws, size_t ws_size,
                              hipStream_t stream) {
    const float* x          = (const float*)d_in[0];
    const int*   edge_index = (const int*)d_in[1];
    const int*   edge_type  = (const int*)d_in[2];
    const float* W          = (const float*)d_in[3];
    const float* root       = (const float*)d_in[4];
    const float* bias       = (const float*)d_in[5];
    float* out = (float*)d_out;

    const int n_nodes = in_sizes[0] / D;          // 100000
    const int n_edges = in_sizes[2];              // 600000
    const int n_rel   = in_sizes[3] / (D * D);    // 8
    const int nsegs   = n_rel + 1;
    const int nG      = n_nodes * nsegs;          // 900000

    // ws layout (worst-case compact rows = n_nodes + n_edges)
    char* p = (char*)d_ws;
    auto alloc = [&](size_t bytes) {
        char* q = p; p += (bytes + 255) & ~(size_t)255; return q;
    };
    int* G      = (int*)alloc((size_t)(nG + 1) * 4);
    int* tmp    = (int*)alloc((size_t)(nG + 1) * 4);
    int* parts  = (int*)alloc(4096);
    int* offs   = (int*)alloc(4096);
    int* tot    = (int*)alloc(256);
    int* erank  = (int*)alloc((size_t)n_edges * 4);
    unsigned* pk2 = (unsigned*)alloc((size_t)n_edges * 4);
    unsigned* XB  = (unsigned*)alloc((size_t)n_nodes * (D / 2) * 4);
    unsigned short* WT = (unsigned short*)alloc((size_t)nsegs * D * D * 2);
    int* csrc   = (int*)alloc((size_t)n_edges * 4);
    unsigned short* H = (unsigned short*)p;       // worst (n_nodes+n_edges) rows

    const int nquads   = n_nodes * (D / 4);
    const int wt_total = nsegs * D * D;
    int conv_n = nquads;
    if (wt_total > conv_n) conv_n = wt_total;

    const int egrid = (n_edges + 255) / 256;
    const int conv_blocks = (conv_n + 255) / 256;
    const int nA = (nG + 1023) / 1024;            // 879 <= 1024

    zero_ws<<<(nG + 1 + 255) / 256, 256, 0, stream>>>(G, nG);
    prep_hist<<<egrid + conv_blocks, 256, 0, stream>>>(
        x, W, root, edge_index, edge_type, XB, WT, G, erank,
        nquads, wt_total, n_edges, n_nodes, n_rel, egrid);
    scanA<<<nA, 1024, 0, stream>>>(G, tmp, parts, nG);
    scanB<<<1, 1024, 0, stream>>>(parts, offs, tot, nA);
    edge_bin<<<egrid, 256, 0, stream>>>(
        edge_index, edge_type, tmp, offs, erank, pk2, csrc,
        n_edges, n_nodes, n_rel);
    gemm_h<<<512, 256, 0, stream>>>(
        XB, WT, bias, csrc, tmp, offs, tot, H, n_nodes, n_edges, n_rel);
    gather_out<<<(n_nodes + 3) / 4, 256, 0, stream>>>(
        H, pk2, tmp, offs, out, n_nodes);
}